// Round 1
// baseline (928.999 us; speedup 1.0000x reference)
//
#include <hip/hip_runtime.h>
#include <cstdint>
#include <cstddef>

// Problem constants
#define Bn 16
#define Tn 128
#define Dn 8192    // C*H*W
#define Fn 16      // NUM_FEAT
#define Gn 4096    // NUM_FEAT*H*W
#define MT (Bn*Tn) // 2048 rows

typedef __attribute__((ext_vector_type(8))) short short8;
typedef __attribute__((ext_vector_type(4))) float f32x4;

__device__ inline short f2bf(float f) {
    union { float f; uint32_t u; } c; c.f = f;
    uint32_t u = c.u;
    uint32_t r = (u + 0x7FFFu + ((u >> 16) & 1u)) >> 16;
    return (short)(r & 0xFFFFu);
}

__device__ inline short8 cvt8(float4 a, float4 b) {
    short8 v;
    v[0] = f2bf(a.x); v[1] = f2bf(a.y); v[2] = f2bf(a.z); v[3] = f2bf(a.w);
    v[4] = f2bf(b.x); v[5] = f2bf(b.y); v[6] = f2bf(b.z); v[7] = f2bf(b.w);
    return v;
}

// ---------------------------------------------------------------------------
// Kernel 1: q = x1 @ w1^T + b1 ; k = x2 @ w2^T + b2   (fp32, exact-ish)
// grid 256 blocks x 256 threads; each block handles 8 (b,t) rows.
// 32 groups of 8 threads: groups 0..15 -> q feature f, groups 16..31 -> k.
// ---------------------------------------------------------------------------
__global__ __launch_bounds__(256) void qk_kernel(
    const float* __restrict__ x1, const float* __restrict__ x2,
    const float* __restrict__ w1, const float* __restrict__ b1,
    const float* __restrict__ w2, const float* __restrict__ b2,
    float* __restrict__ q, float* __restrict__ k)
{
    const int g  = threadIdx.x >> 3;   // 0..31
    const int l8 = threadIdx.x & 7;    // 0..7
    const int f  = g & 15;
    const bool isQ = (g < 16);
    const float* x = isQ ? x1 : x2;
    const float* w = (isQ ? w1 : w2) + (size_t)f * Dn;
    const float* bias = isQ ? b1 : b2;
    float* outp = isQ ? q : k;

    #pragma unroll 1
    for (int r = 0; r < 8; ++r) {
        const int bt = blockIdx.x * 8 + r;
        const float4* xr = (const float4*)(x + (size_t)bt * Dn);
        const float4* wr = (const float4*)w;
        float acc = 0.f;
        #pragma unroll 4
        for (int c = l8; c < Dn / 4; c += 8) {
            float4 xv = xr[c];
            float4 wv = wr[c];
            acc += xv.x * wv.x + xv.y * wv.y + xv.z * wv.z + xv.w * wv.w;
        }
        acc += __shfl_xor(acc, 4, 64);
        acc += __shfl_xor(acc, 2, 64);
        acc += __shfl_xor(acc, 1, 64);
        if (l8 == 0) outp[bt * Fn + f] = acc + bias[f];
    }
}

// ---------------------------------------------------------------------------
// Kernel 2: scores = q @ k^T per batch; attn = softmax over t (axis=1!)
// One block (128 threads) per batch; thread s owns column s.
// Two passes over t (online max+sum, then normalize+write). Recompute is cheap.
// ---------------------------------------------------------------------------
__global__ __launch_bounds__(128) void attn_kernel(
    const float* __restrict__ q, const float* __restrict__ k,
    float* __restrict__ attn)
{
    __shared__ float qs[Tn * 17];  // padded stride 17 to break bank conflicts
    const int b = blockIdx.x;
    const int tid = threadIdx.x;   // = s, 0..127

    for (int i = tid; i < Tn * Fn; i += 128)
        qs[(i >> 4) * 17 + (i & 15)] = q[b * Tn * Fn + i];
    __syncthreads();

    float kr[16];
    #pragma unroll
    for (int f = 0; f < 16; ++f) kr[f] = k[b * Tn * Fn + tid * Fn + f];

    float m = -1e30f, sum = 0.f;
    #pragma unroll 1
    for (int t = 0; t < Tn; ++t) {
        float sc = 0.f;
        #pragma unroll
        for (int f = 0; f < 16; ++f) sc += qs[t * 17 + f] * kr[f];
        if (sc > m) { sum = sum * __expf(m - sc) + 1.f; m = sc; }
        else        { sum += __expf(sc - m); }
    }
    const float inv = 1.f / sum;
    float* ap = attn + (size_t)b * Tn * Tn;
    #pragma unroll 1
    for (int t = 0; t < Tn; ++t) {
        float sc = 0.f;
        #pragma unroll
        for (int f = 0; f < 16; ++f) sc += qs[t * 17 + f] * kr[f];
        ap[t * Tn + tid] = __expf(sc - m) * inv;  // coalesced across s
    }
}

// ---------------------------------------------------------------------------
// Kernel 3: v = x1 @ w3^T + b3  — the 137 GFLOP GEMM, bf16 MFMA.
// A = x1 [2048,8192] fp32 row-major, Bw = w3 [4096,8192] fp32 row-major.
// 128x128 C-tile per 256-thread block (4 waves, each 64x64 = 4x4 MFMA tiles).
// Inline fp32->bf16 convert during LDS staging. LDS stride 40 (pad 8) keeps
// ds_read_b128 16B-aligned and spreads banks.
// ---------------------------------------------------------------------------
#define LDK 40

__global__ __launch_bounds__(256) void gemm_v_kernel(
    const float* __restrict__ A, const float* __restrict__ Bw,
    const float* __restrict__ bias, float* __restrict__ C)
{
    __shared__ __attribute__((aligned(16))) short As[128 * LDK];
    __shared__ __attribute__((aligned(16))) short Bs[128 * LDK];

    const int tid = threadIdx.x;
    const int m0 = blockIdx.y * 128;
    const int n0 = blockIdx.x * 128;
    const int wave = tid >> 6, lane = tid & 63;
    const int wm = (wave >> 1) * 64, wn = (wave & 1) * 64;
    const int quad = lane >> 4, r = lane & 15;

    const int srow = tid >> 2;        // 0..63
    const int scol = (tid & 3) * 8;   // 0,8,16,24 (floats / bf16 elems)

    f32x4 acc[4][4] = {};

    #pragma unroll 1
    for (int k0 = 0; k0 < Dn; k0 += 32) {
        __syncthreads();
        #pragma unroll
        for (int rep = 0; rep < 2; ++rep) {
            const int row = srow + rep * 64;
            const float4* ap = (const float4*)(A  + (size_t)(m0 + row) * Dn + k0 + scol);
            const float4* bp = (const float4*)(Bw + (size_t)(n0 + row) * Dn + k0 + scol);
            float4 a0 = ap[0], a1 = ap[1];
            float4 b0 = bp[0], b1 = bp[1];
            *(short8*)&As[row * LDK + scol] = cvt8(a0, a1);
            *(short8*)&Bs[row * LDK + scol] = cvt8(b0, b1);
        }
        __syncthreads();

        short8 af[4], bf[4];
        #pragma unroll
        for (int i = 0; i < 4; ++i)
            af[i] = *(const short8*)&As[(wm + i * 16 + r) * LDK + quad * 8];
        #pragma unroll
        for (int j = 0; j < 4; ++j)
            bf[j] = *(const short8*)&Bs[(wn + j * 16 + r) * LDK + quad * 8];

        #pragma unroll
        for (int i = 0; i < 4; ++i)
            #pragma unroll
            for (int j = 0; j < 4; ++j)
                acc[i][j] = __builtin_amdgcn_mfma_f32_16x16x32_bf16(
                    af[i], bf[j], acc[i][j], 0, 0, 0);
    }

    // Epilogue: C/D layout col=lane&15 (n), row=quad*4+reg (m). Add bias.
    #pragma unroll
    for (int j = 0; j < 4; ++j) {
        const int col = n0 + wn + j * 16 + r;
        const float bv = bias[col];
        #pragma unroll
        for (int i = 0; i < 4; ++i) {
            #pragma unroll
            for (int reg = 0; reg < 4; ++reg) {
                const int rowg = m0 + wm + i * 16 + quad * 4 + reg;
                C[(size_t)rowg * Gn + col] = acc[i][j][reg] + bv;
            }
        }
    }
}

// ---------------------------------------------------------------------------
// Kernel 4: out[b,t,g] = sum_s attn[b,t,s] * v[b,s,g]
// grid (Gn/256, Tn/16, Bn); thread owns one g, accumulates 16 t's.
// ---------------------------------------------------------------------------
__global__ __launch_bounds__(256) void out_kernel(
    const float* __restrict__ attn, const float* __restrict__ v,
    float* __restrict__ out)
{
    __shared__ float a_s[16 * Tn];
    const int b = blockIdx.z;
    const int t0 = blockIdx.y * 16;
    const int g = blockIdx.x * 256 + threadIdx.x;

    const float* ab = attn + (size_t)b * Tn * Tn + (size_t)t0 * Tn;
    for (int i = threadIdx.x; i < 16 * Tn; i += 256) a_s[i] = ab[i];
    __syncthreads();

    float acc[16];
    #pragma unroll
    for (int tt = 0; tt < 16; ++tt) acc[tt] = 0.f;

    const float* vb = v + (size_t)b * Tn * Gn + g;
    #pragma unroll 4
    for (int s = 0; s < Tn; ++s) {
        const float vs = vb[(size_t)s * Gn];
        #pragma unroll
        for (int tt = 0; tt < 16; ++tt)
            acc[tt] += a_s[tt * Tn + s] * vs;   // LDS broadcast (uniform addr)
    }

    float* ob = out + (size_t)b * Tn * Gn + (size_t)t0 * Gn + g;
    #pragma unroll
    for (int tt = 0; tt < 16; ++tt) ob[(size_t)tt * Gn] = acc[tt];
}

// ---------------------------------------------------------------------------
extern "C" void kernel_launch(void* const* d_in, const int* in_sizes, int n_in,
                              void* d_out, int out_size, void* d_ws, size_t ws_size,
                              hipStream_t stream)
{
    const float* x1 = (const float*)d_in[0];
    const float* x2 = (const float*)d_in[1];
    const float* w1 = (const float*)d_in[2];
    const float* b1 = (const float*)d_in[3];
    const float* w2 = (const float*)d_in[4];
    const float* b2 = (const float*)d_in[5];
    const float* w3 = (const float*)d_in[6];
    const float* b3 = (const float*)d_in[7];
    float* out = (float*)d_out;

    // Workspace layout (fp32): q[2048*16] k[2048*16] attn[16*128*128] v[2048*4096]
    float* q    = (float*)d_ws;
    float* k    = q + MT * Fn;
    float* attn = k + MT * Fn;
    float* v    = attn + (size_t)Bn * Tn * Tn;   // 33.25 MB total

    qk_kernel<<<256, 256, 0, stream>>>(x1, x2, w1, b1, w2, b2, q, k);
    attn_kernel<<<Bn, 128, 0, stream>>>(q, k, attn);
    gemm_v_kernel<<<dim3(Gn / 128, MT / 128), 256, 0, stream>>>(x1, w3, b3, v);
    out_kernel<<<dim3(Gn / 256, Tn / 16, Bn), 256, 0, stream>>>(attn, v, out);
}